// Round 10
// baseline (190.542 us; speedup 1.0000x reference)
//
#include <hip/hip_runtime.h>
#include <math.h>

namespace {

constexpr int B = 16, N = 512, H = 8, D = 32, E = 16, HID = 256;
constexpr float SCALE = 0.17677669529663687f;  // 32^-0.5
constexpr size_t HSZ = (size_t)B * H * N * D;  // 2,097,152 elements (= B*N*HID)
constexpr size_t WSZ = (size_t)HID * HID;      // 65,536
constexpr int CONV_BLOCKS = 6400;              // (3*HSZ + 4*WSZ)/4 elems / 256

typedef __attribute__((ext_vector_type(8))) short short8;
typedef __attribute__((ext_vector_type(4))) float float4v;

__device__ inline short f2bf(float x) {  // fp32 -> bf16 bits, RNE (finite inputs)
  union { float f; unsigned u; } v; v.f = x;
  unsigned r = v.u + 0x7fffu + ((v.u >> 16) & 1u);
  return (short)(r >> 16);
}

// ---------------------------------------------------------------------------
// Mega-prep (one launch):
//  blocks [0,6400): fp32->bf16 convert of q,k,v,Wq,Wk,Wv,Wo (4 elems/thread)
//  blocks [6400,6912): pack tiles: packed[b][it][j][m] = e | focal<<4|mask<<5.
//    Each pack block self-detects mask storage (int32 0/1 words OR to <=1;
//    byte-packed bools OR to >1) from the first 4KB of fmask.
// ---------------------------------------------------------------------------
__global__ __launch_bounds__(256) void prep_kernel(
    const float* __restrict__ q, const float* __restrict__ k, const float* __restrict__ v,
    const float* __restrict__ Wq, const float* __restrict__ Wk,
    const float* __restrict__ Wv, const float* __restrict__ Wo,
    unsigned short* __restrict__ qx, unsigned short* __restrict__ kx,
    unsigned short* __restrict__ vx, unsigned short* __restrict__ wq,
    unsigned short* __restrict__ wk, unsigned short* __restrict__ wv,
    unsigned short* __restrict__ wo,
    const int* __restrict__ ea, const void* __restrict__ maskp,
    const void* __restrict__ fmaskp, unsigned char* __restrict__ packed)
{
  __shared__ unsigned char tl[16 * 520];
  __shared__ unsigned sdet[4];
  const int bid = blockIdx.x, t = threadIdx.x;

  if (bid < CONV_BLOCKS) {
    constexpr size_t H4 = HSZ / 4;
    constexpr size_t W4 = WSZ / 4;
    const size_t idx = (size_t)bid * 256 + t;
    const float* src; unsigned short* dst; size_t off;
    if (idx < H4)            { src = q; dst = qx; off = idx; }
    else if (idx < 2 * H4)   { src = k; dst = kx; off = idx - H4; }
    else if (idx < 3 * H4)   { src = v; dst = vx; off = idx - 2 * H4; }
    else {
      const size_t r = idx - 3 * H4;
      const int wsel = (int)(r / W4); off = r % W4;
      src = (wsel == 0) ? Wq : (wsel == 1) ? Wk : (wsel == 2) ? Wv : Wo;
      dst = (wsel == 0) ? wq : (wsel == 1) ? wk : (wsel == 2) ? wv : wo;
    }
    const float4 f = ((const float4*)src)[off];
    ushort4 o;
    o.x = (unsigned short)f2bf(f.x); o.y = (unsigned short)f2bf(f.y);
    o.z = (unsigned short)f2bf(f.z); o.w = (unsigned short)f2bf(f.w);
    ((ushort4*)dst)[off] = o;
    return;
  }

  // ---- pack branch ----
  const int pb = bid - CONV_BLOCKS;
  const int it = pb & 31, b = pb >> 5;
  const int i0 = it * 16;
  const int w = t >> 6, lane = t & 63;
  const unsigned* fm_u = (const unsigned*)fmaskp;
  unsigned o = 0;
#pragma unroll
  for (int i = 0; i < 4; ++i) o |= fm_u[t + i * 256];
  o |= __shfl_xor(o, 1);  o |= __shfl_xor(o, 2);  o |= __shfl_xor(o, 4);
  o |= __shfl_xor(o, 8);  o |= __shfl_xor(o, 16); o |= __shfl_xor(o, 32);
  if (lane == 0) sdet[w] = o;
  __syncthreads();
  const int bf = ((sdet[0] | sdet[1] | sdet[2] | sdet[3]) > 1u) ? 1 : 0;

  const int* fm32 = (const int*)fmaskp;
  const unsigned char* fm8 = (const unsigned char*)fmaskp;
  const int* mk32 = (const int*)maskp;
  const unsigned char* mk8 = (const unsigned char*)maskp;

  for (int idx4 = t; idx4 < 2048; idx4 += 256) {
    const int m = idx4 >> 7, j4 = (idx4 & 127) * 4;
    const size_t rowoff = ((size_t)(b * N) + i0 + m) * N;
    const int4 e4 = *(const int4*)(ea + rowoff + j4);
    int fv0, fv1, fv2, fv3, mv0, mv1, mv2, mv3;
    if (bf) {
      const unsigned fw = *(const unsigned*)(fm8 + rowoff + j4);
      fv0 = fw & 0xff; fv1 = (fw >> 8) & 0xff; fv2 = (fw >> 16) & 0xff; fv3 = fw >> 24;
      const unsigned mw = *(const unsigned*)(mk8 + b * N + j4);
      mv0 = mw & 0xff; mv1 = (mw >> 8) & 0xff; mv2 = (mw >> 16) & 0xff; mv3 = mw >> 24;
    } else {
      const int4 fw = *(const int4*)(fm32 + rowoff + j4);
      fv0 = fw.x; fv1 = fw.y; fv2 = fw.z; fv3 = fw.w;
      const int4 mw = *(const int4*)(mk32 + b * N + j4);
      mv0 = mw.x; mv1 = mw.y; mv2 = mw.z; mv3 = mw.w;
    }
    const unsigned b0 = (e4.x & 15) | (fv0 ? 16u : 0u) | (mv0 ? 32u : 0u);
    const unsigned b1 = (e4.y & 15) | (fv1 ? 16u : 0u) | (mv1 ? 32u : 0u);
    const unsigned b2 = (e4.z & 15) | (fv2 ? 16u : 0u) | (mv2 ? 32u : 0u);
    const unsigned b3 = (e4.w & 15) | (fv3 ? 16u : 0u) | (mv3 ? 32u : 0u);
    *(unsigned*)&tl[m * 520 + j4] = b0 | (b1 << 8) | (b2 << 16) | (b3 << 24);
  }
  __syncthreads();
#pragma unroll
  for (int rep = 0; rep < 2; ++rep) {
    const int j = t * 2 + rep;
    unsigned wd[4];
#pragma unroll
    for (int g = 0; g < 4; ++g) {
      const unsigned c0 = tl[(g * 4 + 0) * 520 + j];
      const unsigned c1 = tl[(g * 4 + 1) * 520 + j];
      const unsigned c2 = tl[(g * 4 + 2) * 520 + j];
      const unsigned c3 = tl[(g * 4 + 3) * 520 + j];
      wd[g] = c0 | (c1 << 8) | (c2 << 16) | (c3 << 24);
    }
    *(uint4*)(packed + ((size_t)(b * 32 + it) * 512 + j) * 16) =
        make_uint4(wd[0], wd[1], wd[2], wd[3]);
  }
}

// ---------------------------------------------------------------------------
// Fused Q/K/V projection GEMM, all-bf16 staging. z=0 -> qh headed [B,H,N,D],
// z=1 -> kh headed, z=2 -> V transposed [B,H,D,N] via LDS tile (coalesced).
// 64x64 tile, BK=64.
// ---------------------------------------------------------------------------
__global__ __launch_bounds__(256) void gemm_qkv(
    const unsigned short* __restrict__ Xq, const unsigned short* __restrict__ Xk,
    const unsigned short* __restrict__ Xv,
    const unsigned short* __restrict__ Wq, const unsigned short* __restrict__ Wk,
    const unsigned short* __restrict__ Wv,
    const float* __restrict__ bq, const float* __restrict__ bk,
    const float* __restrict__ bv,
    unsigned short* __restrict__ qh, unsigned short* __restrict__ kh,
    unsigned short* __restrict__ vt)
{
  __shared__ __align__(16) unsigned short As[64][72];
  __shared__ __align__(16) unsigned short Bs[64][72];
  const int z = blockIdx.z;
  const unsigned short* X = (z == 0) ? Xq : (z == 1) ? Xk : Xv;
  const unsigned short* W = (z == 0) ? Wq : (z == 1) ? Wk : Wv;
  const float* bias = (z == 0) ? bq : (z == 1) ? bk : bv;

  const int m0 = blockIdx.x * 64, n0 = blockIdx.y * 64;
  const int t = threadIdx.x, lane = t & 63, w = t >> 6;
  const int quad = lane >> 4, col = lane & 15;
  const int wm = (w & 1) * 32, wn = (w >> 1) * 32;
  const int srow = t >> 2, skk = (t & 3) * 16;
  float4v acc[2][2] = {{{0,0,0,0},{0,0,0,0}},{{0,0,0,0},{0,0,0,0}}};

  for (int kit = 0; kit < 4; ++kit) {
    const int k0 = kit * 64;
    {
      const unsigned short* xp = X + (size_t)(m0 + srow) * HID + k0 + skk;
      const unsigned short* wp = W + (size_t)(n0 + srow) * HID + k0 + skk;
      *(short8*)&As[srow][skk] = *(const short8*)xp;
      *(short8*)&As[srow][skk + 8] = *(const short8*)(xp + 8);
      *(short8*)&Bs[srow][skk] = *(const short8*)wp;
      *(short8*)&Bs[srow][skk + 8] = *(const short8*)(wp + 8);
    }
    __syncthreads();
#pragma unroll
    for (int ks = 0; ks < 2; ++ks) {
      const int kk = ks * 32 + quad * 8;
      short8 a0 = *(const short8*)&As[wm + col][kk];
      short8 a1 = *(const short8*)&As[wm + 16 + col][kk];
      short8 b0 = *(const short8*)&Bs[wn + col][kk];
      short8 b1 = *(const short8*)&Bs[wn + 16 + col][kk];
      acc[0][0] = __builtin_amdgcn_mfma_f32_16x16x32_bf16(a0, b0, acc[0][0], 0, 0, 0);
      acc[0][1] = __builtin_amdgcn_mfma_f32_16x16x32_bf16(a0, b1, acc[0][1], 0, 0, 0);
      acc[1][0] = __builtin_amdgcn_mfma_f32_16x16x32_bf16(a1, b0, acc[1][0], 0, 0, 0);
      acc[1][1] = __builtin_amdgcn_mfma_f32_16x16x32_bf16(a1, b1, acc[1][1], 0, 0, 0);
    }
    __syncthreads();
  }
  if (z == 2) {
#pragma unroll
    for (int mt = 0; mt < 2; ++mt)
#pragma unroll
      for (int nt = 0; nt < 2; ++nt)
#pragma unroll
        for (int r = 0; r < 4; ++r) {
          const int m_l = wm + mt * 16 + quad * 4 + r;
          const int n_l = wn + nt * 16 + col;
          As[n_l][m_l] = (unsigned short)f2bf(acc[mt][nt][r] + bias[n0 + n_l]);
        }
    __syncthreads();
#pragma unroll
    for (int rep = 0; rep < 16; ++rep) {
      const int flat = rep * 256 + t;
      const int n_l = flat >> 6, m_l = flat & 63;
      const int n = n0 + n_l, m = m0 + m_l;
      const int b_ = m >> 9, ii = m & 511, h_ = n >> 5, d_ = n & 31;
      vt[((size_t)(b_ * H + h_) * D + d_) * N + ii] = As[n_l][m_l];
    }
    return;
  }
#pragma unroll
  for (int mt = 0; mt < 2; ++mt)
#pragma unroll
    for (int nt = 0; nt < 2; ++nt)
#pragma unroll
      for (int r = 0; r < 4; ++r) {
        const int m = m0 + wm + mt * 16 + quad * 4 + r;
        const int n = n0 + wn + nt * 16 + col;
        const float val = acc[mt][nt][r] + bias[n];
        const int b_ = m >> 9, ii = m & 511, h_ = n >> 5, d_ = n & 31;
        unsigned short* Yh = (z == 0) ? qh : kh;
        Yh[((size_t)(b_ * H + h_) * N + ii) * D + d_] = (unsigned short)f2bf(val);
      }
}

// ---------------------------------------------------------------------------
// Output GEMM: Y = ctx(bf16) @ Wo^T(bf16) + bias, fp32 flat out. BK=64.
// ---------------------------------------------------------------------------
__global__ __launch_bounds__(256) void gemm_out(
    const unsigned short* __restrict__ X, const unsigned short* __restrict__ W,
    const float* __restrict__ bias, float* __restrict__ Yf)
{
  __shared__ __align__(16) unsigned short As[64][72];
  __shared__ __align__(16) unsigned short Bs[64][72];
  const int m0 = blockIdx.x * 64, n0 = blockIdx.y * 64;
  const int t = threadIdx.x, lane = t & 63, w = t >> 6;
  const int quad = lane >> 4, col = lane & 15;
  const int wm = (w & 1) * 32, wn = (w >> 1) * 32;
  const int srow = t >> 2, skk = (t & 3) * 16;
  float4v acc[2][2] = {{{0,0,0,0},{0,0,0,0}},{{0,0,0,0},{0,0,0,0}}};

  for (int kit = 0; kit < 4; ++kit) {
    const int k0 = kit * 64;
    {
      const unsigned short* xp = X + (size_t)(m0 + srow) * HID + k0 + skk;
      const unsigned short* wp = W + (size_t)(n0 + srow) * HID + k0 + skk;
      *(short8*)&As[srow][skk] = *(const short8*)xp;
      *(short8*)&As[srow][skk + 8] = *(const short8*)(xp + 8);
      *(short8*)&Bs[srow][skk] = *(const short8*)wp;
      *(short8*)&Bs[srow][skk + 8] = *(const short8*)(wp + 8);
    }
    __syncthreads();
#pragma unroll
    for (int ks = 0; ks < 2; ++ks) {
      const int kk = ks * 32 + quad * 8;
      short8 a0 = *(const short8*)&As[wm + col][kk];
      short8 a1 = *(const short8*)&As[wm + 16 + col][kk];
      short8 b0 = *(const short8*)&Bs[wn + col][kk];
      short8 b1 = *(const short8*)&Bs[wn + 16 + col][kk];
      acc[0][0] = __builtin_amdgcn_mfma_f32_16x16x32_bf16(a0, b0, acc[0][0], 0, 0, 0);
      acc[0][1] = __builtin_amdgcn_mfma_f32_16x16x32_bf16(a0, b1, acc[0][1], 0, 0, 0);
      acc[1][0] = __builtin_amdgcn_mfma_f32_16x16x32_bf16(a1, b0, acc[1][0], 0, 0, 0);
      acc[1][1] = __builtin_amdgcn_mfma_f32_16x16x32_bf16(a1, b1, acc[1][1], 0, 0, 0);
    }
    __syncthreads();
  }
#pragma unroll
  for (int mt = 0; mt < 2; ++mt)
#pragma unroll
    for (int nt = 0; nt < 2; ++nt)
#pragma unroll
      for (int r = 0; r < 4; ++r) {
        const int m = m0 + wm + mt * 16 + quad * 4 + r;
        const int n = n0 + wn + nt * 16 + col;
        Yf[(size_t)m * HID + n] = acc[mt][nt][r] + bias[n];
      }
}

// ---------------------------------------------------------------------------
// MFMA attention, head-pair per block, wave-autonomous online softmax.
// qes computed via 2 MFMAs per wave (fragments straight from global, inline
// bf16 convert) -- no LDS staging prologue. O accumulators for both heads
// stay in VGPRs through the h2 loop; after P's last read the wave writes them
// into its own P slice (SMEM alias, barrier-fenced). LDS ~21.3 KB.
// ---------------------------------------------------------------------------
__global__ __launch_bounds__(256) void attn_mfma(
    const unsigned short* __restrict__ qh, const unsigned short* __restrict__ kh,
    const unsigned short* __restrict__ vt,
    const float* __restrict__ qemb, const float* __restrict__ kemb,
    const unsigned char* __restrict__ packed, unsigned short* __restrict__ ctx)
{
  // per-wave 4352B slice: P [16][136] shorts, later ored [2][16][33] floats
  __shared__ __align__(16) unsigned char SMEM[4][4352];
  __shared__ float qesS[2][16][17];
  __shared__ float2 wlm[4][2][16];
  __shared__ float scl[4][32];
  __shared__ float linv[32];

  const int it = blockIdx.x, p = blockIdx.y, b = blockIdx.z;
  const int i0 = it * 16;
  const int t = threadIdx.x, w = t >> 6, lane = t & 63;
  const int quad = lane >> 4, col = lane & 15;

  unsigned short* Pw = (unsigned short*)&SMEM[w][0];   // [16][136]

  // packed words for this wave's 128 keys -> VGPRs
  unsigned pk[8];
  {
    const unsigned char* pt = packed + ((size_t)(b * 32 + it) * 512) * 16;
#pragma unroll
    for (int c = 0; c < 8; ++c)
      pk[c] = *(const unsigned*)(pt + (size_t)(w * 128 + c * 16 + col) * 16 + quad * 4);
  }

  // ---- qes[m][e] = Q.EQ^T + K.EK^T via 2 MFMAs (wave 0 -> h2=0, wave 1 -> h2=1)
  if (w < 2) {
    const int h2w = w;
    const int hp = p + h2w * 4;
    const int bhw = b * H + hp;
    const short8 qa = *(const short8*)(qh + ((size_t)bhw * N + i0 + col) * D + quad * 8);
    const short8 ka = *(const short8*)(kh + ((size_t)bhw * N + i0 + col) * D + quad * 8);
    const float* eqp = qemb + col * 256 + hp * 32 + quad * 8;
    const float* ekp = kemb + col * 256 + hp * 32 + quad * 8;
    const float4 e1 = *(const float4*)eqp, e2 = *(const float4*)(eqp + 4);
    const float4 k1 = *(const float4*)ekp, k2 = *(const float4*)(ekp + 4);
    short8 eb, kb;
    eb[0]=f2bf(e1.x); eb[1]=f2bf(e1.y); eb[2]=f2bf(e1.z); eb[3]=f2bf(e1.w);
    eb[4]=f2bf(e2.x); eb[5]=f2bf(e2.y); eb[6]=f2bf(e2.z); eb[7]=f2bf(e2.w);
    kb[0]=f2bf(k1.x); kb[1]=f2bf(k1.y); kb[2]=f2bf(k1.z); kb[3]=f2bf(k1.w);
    kb[4]=f2bf(k2.x); kb[5]=f2bf(k2.y); kb[6]=f2bf(k2.z); kb[7]=f2bf(k2.w);
    float4v qe = {0, 0, 0, 0};
    qe = __builtin_amdgcn_mfma_f32_16x16x32_bf16(qa, eb, qe, 0, 0, 0);
    qe = __builtin_amdgcn_mfma_f32_16x16x32_bf16(ka, kb, qe, 0, 0, 0);
#pragma unroll
    for (int r = 0; r < 4; ++r)
      qesS[h2w][quad * 4 + r][col] = qe[r] * SCALE;
  }
  __syncthreads();

  float4v oa[2][2] = {{{0,0,0,0},{0,0,0,0}},{{0,0,0,0},{0,0,0,0}}};
#pragma unroll
  for (int h2 = 0; h2 < 2; ++h2) {
    const int bh = b * H + p + h2 * 4;
    const short8 qf = *(const short8*)(qh + ((size_t)bh * N + i0 + col) * D + quad * 8);

    float s[8][4];
#pragma unroll
    for (int c = 0; c < 8; ++c) {
      const int j0 = w * 128 + c * 16;
      const short8 kf = *(const short8*)(kh + ((size_t)bh * N + j0 + col) * D + quad * 8);
      float4v sc = {0, 0, 0, 0};
      sc = __builtin_amdgcn_mfma_f32_16x16x32_bf16(qf, kf, sc, 0, 0, 0);
#pragma unroll
      for (int r = 0; r < 4; ++r) {
        const int m = quad * 4 + r;
        const unsigned by = pk[c] >> (8 * r);
        const int e = by & 15;
        const int valid = h2 ? (by >> 4) & 1 : (by >> 5) & 1;
        const float sv = fmaf(sc[r], SCALE, qesS[h2][m][e]);
        s[c][r] = valid ? sv : -INFINITY;
      }
    }

    float mW[4];
#pragma unroll
    for (int r = 0; r < 4; ++r) {
      float m2 = s[0][r];
#pragma unroll
      for (int c = 1; c < 8; ++c) m2 = fmaxf(m2, s[c][r]);
      m2 = fmaxf(m2, __shfl_xor(m2, 1));
      m2 = fmaxf(m2, __shfl_xor(m2, 2));
      m2 = fmaxf(m2, __shfl_xor(m2, 4));
      m2 = fmaxf(m2, __shfl_xor(m2, 8));
      mW[r] = fmaxf(m2, -3.0e38f);
    }
#pragma unroll
    for (int r = 0; r < 4; ++r) {
      const int m = quad * 4 + r;
      float sm = 0.f;
#pragma unroll
      for (int c = 0; c < 8; ++c) {
        const float ex = __expf(s[c][r] - mW[r]);
        sm += ex;
        Pw[m * 136 + c * 16 + col] = (unsigned short)f2bf(ex);
      }
      sm += __shfl_xor(sm, 1);
      sm += __shfl_xor(sm, 2);
      sm += __shfl_xor(sm, 4);
      sm += __shfl_xor(sm, 8);
      if (col == 0) wlm[w][h2][m] = make_float2(mW[r], sm);
    }

#pragma unroll
    for (int c2 = 0; c2 < 4; ++c2) {
      const int kl = c2 * 32 + quad * 8;
      const short8 pf = *(const short8*)&Pw[col * 136 + kl];
      const int kg = w * 128 + kl;
      const short8 v0 = *(const short8*)(vt + ((size_t)bh * D + col) * N + kg);
      const short8 v1 = *(const short8*)(vt + ((size_t)bh * D + 16 + col) * N + kg);
      oa[h2][0] = __builtin_amdgcn_mfma_f32_16x16x32_bf16(pf, v0, oa[h2][0], 0, 0, 0);
      oa[h2][1] = __builtin_amdgcn_mfma_f32_16x16x32_bf16(pf, v1, oa[h2][1], 0, 0, 0);
    }
  }
  __syncthreads();   // all P reads complete block-wide; SMEM now holds ored

  {
    float* Ow = (float*)&SMEM[w][0];   // [2][16][33]
#pragma unroll
    for (int h2 = 0; h2 < 2; ++h2)
#pragma unroll
      for (int r = 0; r < 4; ++r) {
        const int m = quad * 4 + r;
        Ow[(h2 * 16 + m) * 33 + col] = oa[h2][0][r];
        Ow[(h2 * 16 + m) * 33 + col + 16] = oa[h2][1][r];
      }
  }
  __syncthreads();

  if (t < 128) {
    const int u = t & 3, row = t >> 2, h2 = row >> 4, q = row & 15;
    const float2 s0 = wlm[0][h2][q], s1 = wlm[1][h2][q];
    const float2 s2 = wlm[2][h2][q], s3 = wlm[3][h2][q];
    const float mg = fmaxf(fmaxf(s0.x, s1.x), fmaxf(s2.x, s3.x));
    const float2 sw = (u == 0) ? s0 : (u == 1) ? s1 : (u == 2) ? s2 : s3;
    scl[u][row] = __expf(sw.x - mg);
    if (u == 0) {
      const float ls = s0.y * __expf(s0.x - mg) + s1.y * __expf(s1.x - mg) +
                       s2.y * __expf(s2.x - mg) + s3.y * __expf(s3.x - mg);
      linv[row] = 1.0f / ls;
    }
  }
  __syncthreads();

#pragma unroll
  for (int it2 = 0; it2 < 4; ++it2) {
    const int flat = it2 * 256 + t;
    const int h2 = flat >> 9, rem = flat & 511, q2 = rem >> 5, d = rem & 31;
    const int row = h2 * 16 + q2;
    float val = 0.f;
#pragma unroll
    for (int u = 0; u < 4; ++u)
      val += ((const float*)&SMEM[u][0])[(h2 * 16 + q2) * 33 + d] * scl[u][row];
    ctx[((size_t)(b * N) + i0 + q2) * HID + (p + h2 * 4) * D + d] =
        (unsigned short)f2bf(val * linv[row]);
  }
}

}  // namespace

extern "C" void kernel_launch(void* const* d_in, const int* in_sizes, int n_in,
                              void* d_out, int out_size, void* d_ws, size_t ws_size,
                              hipStream_t stream)
{
  const float* q    = (const float*)d_in[0];
  const float* k    = (const float*)d_in[1];
  const float* v    = (const float*)d_in[2];
  const float* qemb = (const float*)d_in[3];
  const float* kemb = (const float*)d_in[4];
  const int*   ea   = (const int*)d_in[5];
  const void*  mask = d_in[6];
  const void*  fmask= d_in[7];
  const float* Wq = (const float*)d_in[8];
  const float* bq = (const float*)d_in[9];
  const float* Wk = (const float*)d_in[10];
  const float* bk = (const float*)d_in[11];
  const float* Wv = (const float*)d_in[12];
  const float* bv = (const float*)d_in[13];
  const float* Wo = (const float*)d_in[14];
  const float* bo = (const float*)d_in[15];

  unsigned short* ws16 = (unsigned short*)d_ws;
  unsigned short* qhb = ws16;
  unsigned short* khb = qhb + HSZ;
  unsigned short* vtb = khb + HSZ;
  unsigned short* ctx = vtb + HSZ;
  unsigned char* packed = (unsigned char*)(ctx + (size_t)B * N * HID);
  unsigned short* qxb = (unsigned short*)(packed + (size_t)B * N * N);
  unsigned short* kxb = qxb + HSZ;
  unsigned short* vxb = kxb + HSZ;
  unsigned short* wqb = vxb + HSZ;
  unsigned short* wkb = wqb + WSZ;
  unsigned short* wvb = wkb + WSZ;
  unsigned short* wob = wvb + WSZ;

  prep_kernel<<<CONV_BLOCKS + 512, 256, 0, stream>>>(
      q, k, v, Wq, Wk, Wv, Wo, qxb, kxb, vxb, wqb, wkb, wvb, wob,
      ea, mask, fmask, packed);
  gemm_qkv<<<dim3((B * N) / 64, HID / 64, 3), 256, 0, stream>>>(
      qxb, kxb, vxb, wqb, wkb, wvb, bq, bk, bv, qhb, khb, vtb);
  attn_mfma<<<dim3(N / 16, H / 2, B), 256, 0, stream>>>(qhb, khb, vtb, qemb,
                                                        kemb, packed, ctx);
  gemm_out<<<dim3((B * N) / 64, HID / 64), 256, 0, stream>>>(ctx, wob, bo, (float*)d_out);
}

// Round 11
// 184.598 us; speedup vs baseline: 1.0322x; 1.0322x over previous
//
#include <hip/hip_runtime.h>
#include <math.h>

namespace {

constexpr int B = 16, N = 512, H = 8, D = 32, E = 16, HID = 256;
constexpr float SCALE = 0.17677669529663687f;  // 32^-0.5
constexpr size_t HSZ = (size_t)B * H * N * D;  // 2,097,152 elements (= B*N*HID)
constexpr size_t WSZ = (size_t)HID * HID;      // 65,536
constexpr int CONV_BLOCKS = 6400;              // (3*HSZ + 4*WSZ)/4 elems / 256

typedef __attribute__((ext_vector_type(8))) short short8;
typedef __attribute__((ext_vector_type(4))) float float4v;

__device__ inline short f2bf(float x) {  // fp32 -> bf16 bits, RNE (finite inputs)
  union { float f; unsigned u; } v; v.f = x;
  unsigned r = v.u + 0x7fffu + ((v.u >> 16) & 1u);
  return (short)(r >> 16);
}

// ---------------------------------------------------------------------------
// Mega-prep (one launch):
//  blocks [0,6400): fp32->bf16 convert of q,k,v,Wq,Wk,Wv,Wo (4 elems/thread)
//  blocks [6400,6912): pack tiles: packed[b][it][j][m] = e | focal<<4|mask<<5.
//    Each pack block self-detects mask storage (int32 0/1 words OR to <=1;
//    byte-packed bools OR to >1) from the first 4KB of fmask.
// ---------------------------------------------------------------------------
__global__ __launch_bounds__(256) void prep_kernel(
    const float* __restrict__ q, const float* __restrict__ k, const float* __restrict__ v,
    const float* __restrict__ Wq, const float* __restrict__ Wk,
    const float* __restrict__ Wv, const float* __restrict__ Wo,
    unsigned short* __restrict__ qx, unsigned short* __restrict__ kx,
    unsigned short* __restrict__ vx, unsigned short* __restrict__ wq,
    unsigned short* __restrict__ wk, unsigned short* __restrict__ wv,
    unsigned short* __restrict__ wo,
    const int* __restrict__ ea, const void* __restrict__ maskp,
    const void* __restrict__ fmaskp, unsigned char* __restrict__ packed)
{
  __shared__ unsigned char tl[16 * 520];
  __shared__ unsigned sdet[4];
  const int bid = blockIdx.x, t = threadIdx.x;

  if (bid < CONV_BLOCKS) {
    constexpr size_t H4 = HSZ / 4;
    constexpr size_t W4 = WSZ / 4;
    const size_t idx = (size_t)bid * 256 + t;
    const float* src; unsigned short* dst; size_t off;
    if (idx < H4)            { src = q; dst = qx; off = idx; }
    else if (idx < 2 * H4)   { src = k; dst = kx; off = idx - H4; }
    else if (idx < 3 * H4)   { src = v; dst = vx; off = idx - 2 * H4; }
    else {
      const size_t r = idx - 3 * H4;
      const int wsel = (int)(r / W4); off = r % W4;
      src = (wsel == 0) ? Wq : (wsel == 1) ? Wk : (wsel == 2) ? Wv : Wo;
      dst = (wsel == 0) ? wq : (wsel == 1) ? wk : (wsel == 2) ? wv : wo;
    }
    const float4 f = ((const float4*)src)[off];
    ushort4 o;
    o.x = (unsigned short)f2bf(f.x); o.y = (unsigned short)f2bf(f.y);
    o.z = (unsigned short)f2bf(f.z); o.w = (unsigned short)f2bf(f.w);
    ((ushort4*)dst)[off] = o;
    return;
  }

  // ---- pack branch ----
  const int pb = bid - CONV_BLOCKS;
  const int it = pb & 31, b = pb >> 5;
  const int i0 = it * 16;
  const int w = t >> 6, lane = t & 63;
  const unsigned* fm_u = (const unsigned*)fmaskp;
  unsigned o = 0;
#pragma unroll
  for (int i = 0; i < 4; ++i) o |= fm_u[t + i * 256];
  o |= __shfl_xor(o, 1);  o |= __shfl_xor(o, 2);  o |= __shfl_xor(o, 4);
  o |= __shfl_xor(o, 8);  o |= __shfl_xor(o, 16); o |= __shfl_xor(o, 32);
  if (lane == 0) sdet[w] = o;
  __syncthreads();
  const int bf = ((sdet[0] | sdet[1] | sdet[2] | sdet[3]) > 1u) ? 1 : 0;

  const int* fm32 = (const int*)fmaskp;
  const unsigned char* fm8 = (const unsigned char*)fmaskp;
  const int* mk32 = (const int*)maskp;
  const unsigned char* mk8 = (const unsigned char*)maskp;

  for (int idx4 = t; idx4 < 2048; idx4 += 256) {
    const int m = idx4 >> 7, j4 = (idx4 & 127) * 4;
    const size_t rowoff = ((size_t)(b * N) + i0 + m) * N;
    const int4 e4 = *(const int4*)(ea + rowoff + j4);
    int fv0, fv1, fv2, fv3, mv0, mv1, mv2, mv3;
    if (bf) {
      const unsigned fw = *(const unsigned*)(fm8 + rowoff + j4);
      fv0 = fw & 0xff; fv1 = (fw >> 8) & 0xff; fv2 = (fw >> 16) & 0xff; fv3 = fw >> 24;
      const unsigned mw = *(const unsigned*)(mk8 + b * N + j4);
      mv0 = mw & 0xff; mv1 = (mw >> 8) & 0xff; mv2 = (mw >> 16) & 0xff; mv3 = mw >> 24;
    } else {
      const int4 fw = *(const int4*)(fm32 + rowoff + j4);
      fv0 = fw.x; fv1 = fw.y; fv2 = fw.z; fv3 = fw.w;
      const int4 mw = *(const int4*)(mk32 + b * N + j4);
      mv0 = mw.x; mv1 = mw.y; mv2 = mw.z; mv3 = mw.w;
    }
    const unsigned b0 = (e4.x & 15) | (fv0 ? 16u : 0u) | (mv0 ? 32u : 0u);
    const unsigned b1 = (e4.y & 15) | (fv1 ? 16u : 0u) | (mv1 ? 32u : 0u);
    const unsigned b2 = (e4.z & 15) | (fv2 ? 16u : 0u) | (mv2 ? 32u : 0u);
    const unsigned b3 = (e4.w & 15) | (fv3 ? 16u : 0u) | (mv3 ? 32u : 0u);
    *(unsigned*)&tl[m * 520 + j4] = b0 | (b1 << 8) | (b2 << 16) | (b3 << 24);
  }
  __syncthreads();
#pragma unroll
  for (int rep = 0; rep < 2; ++rep) {
    const int j = t * 2 + rep;
    unsigned wd[4];
#pragma unroll
    for (int g = 0; g < 4; ++g) {
      const unsigned c0 = tl[(g * 4 + 0) * 520 + j];
      const unsigned c1 = tl[(g * 4 + 1) * 520 + j];
      const unsigned c2 = tl[(g * 4 + 2) * 520 + j];
      const unsigned c3 = tl[(g * 4 + 3) * 520 + j];
      wd[g] = c0 | (c1 << 8) | (c2 << 16) | (c3 << 24);
    }
    *(uint4*)(packed + ((size_t)(b * 32 + it) * 512 + j) * 16) =
        make_uint4(wd[0], wd[1], wd[2], wd[3]);
  }
}

// ---------------------------------------------------------------------------
// Fused Q/K/V projection GEMM, all-bf16 staging. z=0 -> qh headed [B,H,N,D],
// z=1 -> kh headed, z=2 -> V transposed [B,H,D,N] via LDS tile (coalesced).
// 64x64 tile, BK=64.
// ---------------------------------------------------------------------------
__global__ __launch_bounds__(256) void gemm_qkv(
    const unsigned short* __restrict__ Xq, const unsigned short* __restrict__ Xk,
    const unsigned short* __restrict__ Xv,
    const unsigned short* __restrict__ Wq, const unsigned short* __restrict__ Wk,
    const unsigned short* __restrict__ Wv,
    const float* __restrict__ bq, const float* __restrict__ bk,
    const float* __restrict__ bv,
    unsigned short* __restrict__ qh, unsigned short* __restrict__ kh,
    unsigned short* __restrict__ vt)
{
  __shared__ __align__(16) unsigned short As[64][72];
  __shared__ __align__(16) unsigned short Bs[64][72];
  const int z = blockIdx.z;
  const unsigned short* X = (z == 0) ? Xq : (z == 1) ? Xk : Xv;
  const unsigned short* W = (z == 0) ? Wq : (z == 1) ? Wk : Wv;
  const float* bias = (z == 0) ? bq : (z == 1) ? bk : bv;

  const int m0 = blockIdx.x * 64, n0 = blockIdx.y * 64;
  const int t = threadIdx.x, lane = t & 63, w = t >> 6;
  const int quad = lane >> 4, col = lane & 15;
  const int wm = (w & 1) * 32, wn = (w >> 1) * 32;
  const int srow = t >> 2, skk = (t & 3) * 16;
  float4v acc[2][2] = {{{0,0,0,0},{0,0,0,0}},{{0,0,0,0},{0,0,0,0}}};

  for (int kit = 0; kit < 4; ++kit) {
    const int k0 = kit * 64;
    {
      const unsigned short* xp = X + (size_t)(m0 + srow) * HID + k0 + skk;
      const unsigned short* wp = W + (size_t)(n0 + srow) * HID + k0 + skk;
      *(short8*)&As[srow][skk] = *(const short8*)xp;
      *(short8*)&As[srow][skk + 8] = *(const short8*)(xp + 8);
      *(short8*)&Bs[srow][skk] = *(const short8*)wp;
      *(short8*)&Bs[srow][skk + 8] = *(const short8*)(wp + 8);
    }
    __syncthreads();
#pragma unroll
    for (int ks = 0; ks < 2; ++ks) {
      const int kk = ks * 32 + quad * 8;
      short8 a0 = *(const short8*)&As[wm + col][kk];
      short8 a1 = *(const short8*)&As[wm + 16 + col][kk];
      short8 b0 = *(const short8*)&Bs[wn + col][kk];
      short8 b1 = *(const short8*)&Bs[wn + 16 + col][kk];
      acc[0][0] = __builtin_amdgcn_mfma_f32_16x16x32_bf16(a0, b0, acc[0][0], 0, 0, 0);
      acc[0][1] = __builtin_amdgcn_mfma_f32_16x16x32_bf16(a0, b1, acc[0][1], 0, 0, 0);
      acc[1][0] = __builtin_amdgcn_mfma_f32_16x16x32_bf16(a1, b0, acc[1][0], 0, 0, 0);
      acc[1][1] = __builtin_amdgcn_mfma_f32_16x16x32_bf16(a1, b1, acc[1][1], 0, 0, 0);
    }
    __syncthreads();
  }
  if (z == 2) {
#pragma unroll
    for (int mt = 0; mt < 2; ++mt)
#pragma unroll
      for (int nt = 0; nt < 2; ++nt)
#pragma unroll
        for (int r = 0; r < 4; ++r) {
          const int m_l = wm + mt * 16 + quad * 4 + r;
          const int n_l = wn + nt * 16 + col;
          As[n_l][m_l] = (unsigned short)f2bf(acc[mt][nt][r] + bias[n0 + n_l]);
        }
    __syncthreads();
#pragma unroll
    for (int rep = 0; rep < 16; ++rep) {
      const int flat = rep * 256 + t;
      const int n_l = flat >> 6, m_l = flat & 63;
      const int n = n0 + n_l, m = m0 + m_l;
      const int b_ = m >> 9, ii = m & 511, h_ = n >> 5, d_ = n & 31;
      vt[((size_t)(b_ * H + h_) * D + d_) * N + ii] = As[n_l][m_l];
    }
    return;
  }
#pragma unroll
  for (int mt = 0; mt < 2; ++mt)
#pragma unroll
    for (int nt = 0; nt < 2; ++nt)
#pragma unroll
      for (int r = 0; r < 4; ++r) {
        const int m = m0 + wm + mt * 16 + quad * 4 + r;
        const int n = n0 + wn + nt * 16 + col;
        const float val = acc[mt][nt][r] + bias[n];
        const int b_ = m >> 9, ii = m & 511, h_ = n >> 5, d_ = n & 31;
        unsigned short* Yh = (z == 0) ? qh : kh;
        Yh[((size_t)(b_ * H + h_) * N + ii) * D + d_] = (unsigned short)f2bf(val);
      }
}

// ---------------------------------------------------------------------------
// Output GEMM: Y = ctx(bf16) @ Wo^T(bf16) + bias, fp32 flat out. BK=64.
// ---------------------------------------------------------------------------
__global__ __launch_bounds__(256) void gemm_out(
    const unsigned short* __restrict__ X, const unsigned short* __restrict__ W,
    const float* __restrict__ bias, float* __restrict__ Yf)
{
  __shared__ __align__(16) unsigned short As[64][72];
  __shared__ __align__(16) unsigned short Bs[64][72];
  const int m0 = blockIdx.x * 64, n0 = blockIdx.y * 64;
  const int t = threadIdx.x, lane = t & 63, w = t >> 6;
  const int quad = lane >> 4, col = lane & 15;
  const int wm = (w & 1) * 32, wn = (w >> 1) * 32;
  const int srow = t >> 2, skk = (t & 3) * 16;
  float4v acc[2][2] = {{{0,0,0,0},{0,0,0,0}},{{0,0,0,0},{0,0,0,0}}};

  for (int kit = 0; kit < 4; ++kit) {
    const int k0 = kit * 64;
    {
      const unsigned short* xp = X + (size_t)(m0 + srow) * HID + k0 + skk;
      const unsigned short* wp = W + (size_t)(n0 + srow) * HID + k0 + skk;
      *(short8*)&As[srow][skk] = *(const short8*)xp;
      *(short8*)&As[srow][skk + 8] = *(const short8*)(xp + 8);
      *(short8*)&Bs[srow][skk] = *(const short8*)wp;
      *(short8*)&Bs[srow][skk + 8] = *(const short8*)(wp + 8);
    }
    __syncthreads();
#pragma unroll
    for (int ks = 0; ks < 2; ++ks) {
      const int kk = ks * 32 + quad * 8;
      short8 a0 = *(const short8*)&As[wm + col][kk];
      short8 a1 = *(const short8*)&As[wm + 16 + col][kk];
      short8 b0 = *(const short8*)&Bs[wn + col][kk];
      short8 b1 = *(const short8*)&Bs[wn + 16 + col][kk];
      acc[0][0] = __builtin_amdgcn_mfma_f32_16x16x32_bf16(a0, b0, acc[0][0], 0, 0, 0);
      acc[0][1] = __builtin_amdgcn_mfma_f32_16x16x32_bf16(a0, b1, acc[0][1], 0, 0, 0);
      acc[1][0] = __builtin_amdgcn_mfma_f32_16x16x32_bf16(a1, b0, acc[1][0], 0, 0, 0);
      acc[1][1] = __builtin_amdgcn_mfma_f32_16x16x32_bf16(a1, b1, acc[1][1], 0, 0, 0);
    }
    __syncthreads();
  }
#pragma unroll
  for (int mt = 0; mt < 2; ++mt)
#pragma unroll
    for (int nt = 0; nt < 2; ++nt)
#pragma unroll
      for (int r = 0; r < 4; ++r) {
        const int m = m0 + wm + mt * 16 + quad * 4 + r;
        const int n = n0 + wn + nt * 16 + col;
        Yf[(size_t)m * HID + n] = acc[mt][nt][r] + bias[n];
      }
}

// ---------------------------------------------------------------------------
// MFMA attention, ONE head per block (grid 32x8x16 = 4096 blocks), fully
// wave-autonomous: each wave owns 128 keys; computes qes redundantly via 2
// MFMAs into its own LDS slice (same-wave in-order, no barrier); P and the
// O-stash alias the same wave slice (last P reader is this wave). Only 2
// barriers (cross-wave merge). LDS ~22.6 KB -> 7 blocks/CU.
// ---------------------------------------------------------------------------
__global__ __launch_bounds__(256) void attn_mfma(
    const unsigned short* __restrict__ qh, const unsigned short* __restrict__ kh,
    const unsigned short* __restrict__ vt,
    const float* __restrict__ qemb, const float* __restrict__ kemb,
    const unsigned char* __restrict__ packed, unsigned short* __restrict__ ctx)
{
  // per-wave 5440B slice: P [16][136] shorts (4352B, later O [16][33] floats
  // aliased over it) + qes [16][17] floats (1088B)
  __shared__ __align__(16) unsigned char SMEM[4][5440];
  __shared__ float2 wlm[4][16];
  __shared__ float scl[4][16];
  __shared__ float linv[16];

  const int it = blockIdx.x, h = blockIdx.y, b = blockIdx.z;
  const int i0 = it * 16, bh = b * H + h;
  const int t = threadIdx.x, w = t >> 6, lane = t & 63;
  const int quad = lane >> 4, col = lane & 15;
  const int mbit = (h < 4) ? 5 : 4;   // heads 0..3 -> mask bit, 4..7 -> focal bit

  unsigned short* Pw = (unsigned short*)&SMEM[w][0];   // [16][136]
  float* qesW = (float*)&SMEM[w][4352];                 // [16][17]

  // packed words for this wave's 128 keys -> VGPRs
  unsigned pk[8];
  {
    const unsigned char* pt = packed + ((size_t)(b * 32 + it) * 512) * 16;
#pragma unroll
    for (int c = 0; c < 8; ++c)
      pk[c] = *(const unsigned*)(pt + (size_t)(w * 128 + c * 16 + col) * 16 + quad * 4);
  }

  // Q fragment for this block's 16 query rows: A[m=col][k=quad*8+j]
  const short8 qf = *(const short8*)(qh + ((size_t)bh * N + i0 + col) * D + quad * 8);

  // ---- qes[m][e] = Q.EQ^T + K.EK^T via 2 MFMAs, wave-private (no barrier) --
  {
    const short8 ka = *(const short8*)(kh + ((size_t)bh * N + i0 + col) * D + quad * 8);
    const float* eqp = qemb + col * 256 + h * 32 + quad * 8;
    const float* ekp = kemb + col * 256 + h * 32 + quad * 8;
    const float4 e1 = *(const float4*)eqp, e2 = *(const float4*)(eqp + 4);
    const float4 k1 = *(const float4*)ekp, k2 = *(const float4*)(ekp + 4);
    short8 eb, kb;
    eb[0]=f2bf(e1.x); eb[1]=f2bf(e1.y); eb[2]=f2bf(e1.z); eb[3]=f2bf(e1.w);
    eb[4]=f2bf(e2.x); eb[5]=f2bf(e2.y); eb[6]=f2bf(e2.z); eb[7]=f2bf(e2.w);
    kb[0]=f2bf(k1.x); kb[1]=f2bf(k1.y); kb[2]=f2bf(k1.z); kb[3]=f2bf(k1.w);
    kb[4]=f2bf(k2.x); kb[5]=f2bf(k2.y); kb[6]=f2bf(k2.z); kb[7]=f2bf(k2.w);
    float4v qe = {0, 0, 0, 0};
    qe = __builtin_amdgcn_mfma_f32_16x16x32_bf16(qf, eb, qe, 0, 0, 0);
    qe = __builtin_amdgcn_mfma_f32_16x16x32_bf16(ka, kb, qe, 0, 0, 0);
#pragma unroll
    for (int r = 0; r < 4; ++r)
      qesW[(quad * 4 + r) * 17 + col] = qe[r] * SCALE;
  }
  // same-wave LDS in-order: qesW reads below are safe without a barrier

  // ---- S for this wave's 128 keys ----
  float s[8][4];
#pragma unroll
  for (int c = 0; c < 8; ++c) {
    const int j0 = w * 128 + c * 16;
    const short8 kf = *(const short8*)(kh + ((size_t)bh * N + j0 + col) * D + quad * 8);
    float4v sc = {0, 0, 0, 0};
    sc = __builtin_amdgcn_mfma_f32_16x16x32_bf16(qf, kf, sc, 0, 0, 0);
#pragma unroll
    for (int r = 0; r < 4; ++r) {
      const int m = quad * 4 + r;
      const unsigned by = pk[c] >> (8 * r);
      const int e = by & 15;
      const int valid = (by >> mbit) & 1;
      const float sv = fmaf(sc[r], SCALE, qesW[m * 17 + e]);
      s[c][r] = valid ? sv : -INFINITY;
    }
  }

  // ---- wave-local softmax over 128 keys ----
  float mW[4];
#pragma unroll
  for (int r = 0; r < 4; ++r) {
    float m2 = s[0][r];
#pragma unroll
    for (int c = 1; c < 8; ++c) m2 = fmaxf(m2, s[c][r]);
    m2 = fmaxf(m2, __shfl_xor(m2, 1));
    m2 = fmaxf(m2, __shfl_xor(m2, 2));
    m2 = fmaxf(m2, __shfl_xor(m2, 4));
    m2 = fmaxf(m2, __shfl_xor(m2, 8));
    mW[r] = fmaxf(m2, -3.0e38f);
  }
#pragma unroll
  for (int r = 0; r < 4; ++r) {
    const int m = quad * 4 + r;
    float sm = 0.f;
#pragma unroll
    for (int c = 0; c < 8; ++c) {
      const float ex = __expf(s[c][r] - mW[r]);
      sm += ex;
      Pw[m * 136 + c * 16 + col] = (unsigned short)f2bf(ex);
    }
    sm += __shfl_xor(sm, 1);
    sm += __shfl_xor(sm, 2);
    sm += __shfl_xor(sm, 4);
    sm += __shfl_xor(sm, 8);
    if (col == 0) wlm[w][m] = make_float2(mW[r], sm);
  }

  // ---- PV over this wave's 128 keys ----
  float4v o0 = {0, 0, 0, 0}, o1 = {0, 0, 0, 0};
#pragma unroll
  for (int c2 = 0; c2 < 4; ++c2) {
    const int kl = c2 * 32 + quad * 8;
    const short8 pf = *(const short8*)&Pw[col * 136 + kl];
    const int kg = w * 128 + kl;
    const short8 v0 = *(const short8*)(vt + ((size_t)bh * D + col) * N + kg);
    const short8 v1 = *(const short8*)(vt + ((size_t)bh * D + 16 + col) * N + kg);
    o0 = __builtin_amdgcn_mfma_f32_16x16x32_bf16(pf, v0, o0, 0, 0, 0);
    o1 = __builtin_amdgcn_mfma_f32_16x16x32_bf16(pf, v1, o1, 0, 0, 0);
  }

  // stash O into the wave slice (aliases P; last P reader was this wave,
  // same-wave LDS ops are in-order -> no barrier needed before overwrite)
  {
    float* Ow = (float*)&SMEM[w][0];   // [16][33]
#pragma unroll
    for (int r = 0; r < 4; ++r) {
      const int m = quad * 4 + r;
      Ow[m * 33 + col] = o0[r];
      Ow[m * 33 + col + 16] = o1[r];
    }
  }
  __syncthreads();   // barrier 1: all waves' Ow + wlm visible

  if (t < 64) {
    const int u = t & 3, q2 = t >> 2;
    const float2 s0 = wlm[0][q2], s1 = wlm[1][q2];
    const float2 s2 = wlm[2][q2], s3 = wlm[3][q2];
    const float mg = fmaxf(fmaxf(s0.x, s1.x), fmaxf(s2.x, s3.x));
    const float2 sw = (u == 0) ? s0 : (u == 1) ? s1 : (u == 2) ? s2 : s3;
    scl[u][q2] = __expf(sw.x - mg);
    if (u == 0) {
      const float ls = s0.y * __expf(s0.x - mg) + s1.y * __expf(s1.x - mg) +
                       s2.y * __expf(s2.x - mg) + s3.y * __expf(s3.x - mg);
      linv[q2] = 1.0f / ls;
    }
  }
  __syncthreads();   // barrier 2: scl/linv ready

#pragma unroll
  for (int rep = 0; rep < 2; ++rep) {
    const int flat = rep * 256 + t;
    const int q2 = flat >> 5, d = flat & 31;
    float val = 0.f;
#pragma unroll
    for (int u = 0; u < 4; ++u)
      val += ((const float*)&SMEM[u][0])[q2 * 33 + d] * scl[u][q2];
    ctx[((size_t)(b * N) + i0 + q2) * HID + h * D + d] =
        (unsigned short)f2bf(val * linv[q2]);
  }
}

}  // namespace

extern "C" void kernel_launch(void* const* d_in, const int* in_sizes, int n_in,
                              void* d_out, int out_size, void* d_ws, size_t ws_size,
                              hipStream_t stream)
{
  const float* q    = (const float*)d_in[0];
  const float* k    = (const float*)d_in[1];
  const float* v    = (const float*)d_in[2];
  const float* qemb = (const float*)d_in[3];
  const float* kemb = (const float*)d_in[4];
  const int*   ea   = (const int*)d_in[5];
  const void*  mask = d_in[6];
  const void*  fmask= d_in[7];
  const float* Wq = (const float*)d_in[8];
  const float* bq = (const float*)d_in[9];
  const float* Wk = (const float*)d_in[10];
  const float* bk = (const float*)d_in[11];
  const float* Wv = (const float*)d_in[12];
  const float* bv = (const float*)d_in[13];
  const float* Wo = (const float*)d_in[14];
  const float* bo = (const float*)d_in[15];

  unsigned short* ws16 = (unsigned short*)d_ws;
  unsigned short* qhb = ws16;
  unsigned short* khb = qhb + HSZ;
  unsigned short* vtb = khb + HSZ;
  unsigned short* ctx = vtb + HSZ;
  unsigned char* packed = (unsigned char*)(ctx + (size_t)B * N * HID);
  unsigned short* qxb = (unsigned short*)(packed + (size_t)B * N * N);
  unsigned short* kxb = qxb + HSZ;
  unsigned short* vxb = kxb + HSZ;
  unsigned short* wqb = vxb + HSZ;
  unsigned short* wkb = wqb + WSZ;
  unsigned short* wvb = wkb + WSZ;
  unsigned short* wob = wvb + WSZ;

  prep_kernel<<<CONV_BLOCKS + 512, 256, 0, stream>>>(
      q, k, v, Wq, Wk, Wv, Wo, qxb, kxb, vxb, wqb, wkb, wvb, wob,
      ea, mask, fmask, packed);
  gemm_qkv<<<dim3((B * N) / 64, HID / 64, 3), 256, 0, stream>>>(
      qxb, kxb, vxb, wqb, wkb, wvb, bq, bk, bv, qhb, khb, vtb);
  attn_mfma<<<dim3(N / 16, H, B), 256, 0, stream>>>(qhb, khb, vtb, qemb,
                                                    kemb, packed, ctx);
  gemm_out<<<dim3((B * N) / 64, HID / 64), 256, 0, stream>>>(ctx, wob, bo, (float*)d_out);
}